// Round 3
// baseline (186.923 us; speedup 1.0000x reference)
//
#include <hip/hip_runtime.h>
#include <math.h>

#define N_TOT 8192
#define D 128
#define JSPLIT 8

typedef unsigned short ushortT;
typedef __attribute__((ext_vector_type(8))) short short8;
typedef __attribute__((ext_vector_type(4))) float f32x4;

// ---------------- bf16 pack (RNE) ----------------
__device__ __forceinline__ unsigned f2bf(float f) {
    unsigned u = __float_as_uint(f);
    return (u + 0x7FFF + ((u >> 16) & 1)) >> 16;
}
__device__ __forceinline__ unsigned pack2(float a, float b) {
    return f2bf(a) | (f2bf(b) << 16);
}

// ---------------- fused normalize->bf16 + pos pack ----------------
// 512 blocks x 256. Each quarter-wave (16 lanes) normalizes one row (4 waves x 4 = 16 rows/block).
__global__ __launch_bounds__(256) void prep_kernel(const float* __restrict__ h,
                                                   const float* __restrict__ pos,
                                                   unsigned* __restrict__ hn2,
                                                   float4* __restrict__ p4) {
    const int tid = threadIdx.x;
    const int wave = tid >> 6, lane = tid & 63;
    const int quad = lane >> 4, l15 = lane & 15;
    const int row = blockIdx.x * 16 + wave * 4 + quad;

    const float4* g = reinterpret_cast<const float4*>(h + (size_t)row * D) + l15 * 2;
    float4 a = g[0], b = g[1];
    float ss = a.x * a.x + a.y * a.y + a.z * a.z + a.w * a.w
             + b.x * b.x + b.y * b.y + b.z * b.z + b.w * b.w;
#pragma unroll
    for (int m = 1; m < 16; m <<= 1) ss += __shfl_xor(ss, m, 64);
    float sc = 1.0f / fmaxf(sqrtf(ss), 1e-12f);

    uint4 o;
    o.x = pack2(a.x * sc, a.y * sc);
    o.y = pack2(a.z * sc, a.w * sc);
    o.z = pack2(b.x * sc, b.y * sc);
    o.w = pack2(b.z * sc, b.w * sc);
    reinterpret_cast<uint4*>(hn2 + (size_t)row * 64)[l15] = o;

    if (tid < 16) {
        int t = blockIdx.x * 16 + tid;
        float x = pos[3 * t], y = pos[3 * t + 1], z = pos[3 * t + 2];
        p4[t] = make_float4(x, y, z, x * x + y * y + z * z);
    }
}

// ---------------- stage a 128x128 bf16 tile via global_load_lds, XOR-swizzled ----------------
// LDS layout: row r (256 B) holds logical 16B-chunk k at physical chunk (k ^ (r&7)).
// global_load_lds writes base + lane*16 (linear), so we pick the per-lane GLOBAL source
// to realize the swizzle.
__device__ __forceinline__ void stage128(const ushortT* __restrict__ src, ushortT* dst,
                                         int wave, int lane) {
#pragma unroll
    for (int it = 0; it < 8; ++it) {
        int c = it * 4 + wave;                       // 1 KB chunk (4 rows)
        int rho = c * 4 + (lane >> 4);               // physical row this lane fills
        int k = (lane & 15) ^ (rho & 7);             // logical chunk to fetch
        const ushortT* g = src + (size_t)rho * D + k * 8;
        __builtin_amdgcn_global_load_lds(
            (const __attribute__((address_space(1))) unsigned int*)g,
            (__attribute__((address_space(3))) unsigned int*)(dst + c * 512),
            16, 0, 0);
    }
}

// swizzled LDS read address (ushort index) for row r, logical chunk k
__device__ __forceinline__ int swz(int r, int k) {
    return r * D + ((k ^ (r & 7)) * 8);
}

// ---------------- fused MFMA sim + softmax partials + positive mask ----------------
__global__ __launch_bounds__(256, 2) void main_kernel(const ushortT* __restrict__ hn,
                                                      const float4* __restrict__ p4,
                                                      float* __restrict__ Ep,
                                                      float* __restrict__ Sp,
                                                      float* __restrict__ Cp) {
    __shared__ ushortT As[128 * D];
    __shared__ ushortT Bs[128 * D];
    const int tid = threadIdx.x;
    const int wave = tid >> 6, lane = tid & 63;
    const int quad = lane >> 4, l15 = lane & 15;
    const int iblock = blockIdx.x * 128;
    const int jstart = blockIdx.y * (N_TOT / JSPLIT);

    stage128(hn + (size_t)iblock * D, As, wave, lane);
    stage128(hn + (size_t)jstart * D, Bs, wave, lane);

    // per-lane anchors: 8 i-rows, i = iblock + wave*32 + r*16 + quad*4 + v
    float pix[8], piy[8], piz[8], qiw[8];
#pragma unroll
    for (int idx = 0; idx < 8; ++idx) {
        int i = iblock + wave * 32 + (idx >> 2) * 16 + quad * 4 + (idx & 3);
        float4 p = p4[i];
        pix[idx] = p.x; piy[idx] = p.y; piz[idx] = p.z; qiw[idx] = 0.5f * p.w;
    }
    float Ea[8], Sa[8];
    int Ci[8];
#pragma unroll
    for (int idx = 0; idx < 8; ++idx) { Ea[idx] = 0.f; Sa[idx] = 0.f; Ci[idx] = 0; }

    __syncthreads();   // drains A + B(0) staging

    // A fragments: constant across all j-tiles -> hoist (8 frags = 32 VGPRs)
    short8 afr[4][2];
#pragma unroll
    for (int ks = 0; ks < 4; ++ks)
#pragma unroll
        for (int r = 0; r < 2; ++r) {
            int ra = wave * 32 + r * 16 + l15;
            afr[ks][r] = *reinterpret_cast<const short8*>(&As[swz(ra, ks * 4 + quad)]);
        }

    for (int jt = 0; jt < 8; ++jt) {
        const int jtbase = jstart + jt * 128;
        if (jt) __syncthreads();              // wait for this tile's staging

        f32x4 acc[2][8];
#pragma unroll
        for (int r = 0; r < 2; ++r)
#pragma unroll
            for (int c = 0; c < 8; ++c) acc[r][c] = (f32x4){0.f, 0.f, 0.f, 0.f};

#pragma unroll
        for (int ks = 0; ks < 4; ++ks) {
            short8 b[8];
#pragma unroll
            for (int c = 0; c < 8; ++c) {
                int rr = c * 16 + l15;
                b[c] = *reinterpret_cast<const short8*>(&Bs[swz(rr, ks * 4 + quad)]);
            }
#pragma unroll
            for (int r = 0; r < 2; ++r)
#pragma unroll
                for (int c = 0; c < 8; ++c)
                    acc[r][c] = __builtin_amdgcn_mfma_f32_16x16x32_bf16(
                        afr[ks][r], b[c], acc[r][c], 0, 0, 0);
        }

        // issue next tile's staging; drains at next loop-top barrier (overlaps epilogue)
        if (jt < 7) {
            __syncthreads();                  // all waves done reading Bs
            stage128(hn + (size_t)(jtbase + 128) * D, Bs, wave, lane);
        }

        if (jtbase != iblock) {
            // ---- non-diagonal tile: no self checks (wave-uniform branch) ----
#pragma unroll
            for (int c = 0; c < 8; ++c) {
                int j = jtbase + c * 16 + l15;
                float4 pj = p4[j];
                float qjw = 0.5f * pj.w - 0.125f;
#pragma unroll
                for (int r = 0; r < 2; ++r)
#pragma unroll
                    for (int v = 0; v < 4; ++v) {
                        int idx = r * 4 + v;
                        float s = acc[r][c][v];
                        Ea[idx] += __expf(fmaf(s, 10.f, -10.f));
                        float dot = fmaf(pix[idx], pj.x, fmaf(piy[idx], pj.y, piz[idx] * pj.z));
                        bool isp = dot > qjw + qiw[idx];
                        Sa[idx] += isp ? s : 0.f;
                        Ci[idx] += isp ? 1 : 0;
                    }
            }
        } else {
            // ---- diagonal tile ----
#pragma unroll
            for (int c = 0; c < 8; ++c) {
                int j = jtbase + c * 16 + l15;
                float4 pj = p4[j];
                float qjw = 0.5f * pj.w - 0.125f;
#pragma unroll
                for (int r = 0; r < 2; ++r)
#pragma unroll
                    for (int v = 0; v < 4; ++v) {
                        int idx = r * 4 + v;
                        float s = acc[r][c][v];
                        bool self = (wave * 32 + r * 16 + quad * 4 + v) == (c * 16 + l15);
                        Ea[idx] += self ? 0.f : __expf(fmaf(s, 10.f, -10.f));
                        float dot = fmaf(pix[idx], pj.x, fmaf(piy[idx], pj.y, piz[idx] * pj.z));
                        bool isp = (dot > qjw + qiw[idx]) && !self;
                        Sa[idx] += isp ? s : 0.f;
                        Ci[idx] += isp ? 1 : 0;
                    }
            }
        }
    }

    // reduce across the 16 lanes (l15) sharing each i-row
#pragma unroll
    for (int idx = 0; idx < 8; ++idx) {
        float Cf = (float)Ci[idx];
#pragma unroll
        for (int m = 1; m < 16; m <<= 1) {
            Ea[idx] += __shfl_xor(Ea[idx], m, 64);
            Sa[idx] += __shfl_xor(Sa[idx], m, 64);
            Cf += __shfl_xor(Cf, m, 64);
        }
        if (l15 == 0) {
            int i = iblock + wave * 32 + (idx >> 2) * 16 + quad * 4 + (idx & 3);
            size_t o = (size_t)blockIdx.y * N_TOT + i;
            Ep[o] = Ea[idx]; Sp[o] = Sa[idx]; Cp[o] = Cf;
        }
    }
}

// ---------------- finalize stage 1: per-anchor loss, per-block partial ----------------
__global__ __launch_bounds__(256) void finalize1_kernel(const float* __restrict__ Ep,
                                                        const float* __restrict__ Sp,
                                                        const float* __restrict__ Cp,
                                                        float2* __restrict__ part) {
    __shared__ float2 wsum[4];
    const int tid = threadIdx.x;
    const int wave = tid >> 6, lane = tid & 63;
    const int a = blockIdx.x * 256 + tid;
    float E = 0.f, S = 0.f, C = 0.f;
#pragma unroll
    for (int s = 0; s < JSPLIT; ++s) {
        E += Ep[(size_t)s * N_TOT + a];
        S += Sp[(size_t)s * N_TOT + a];
        C += Cp[(size_t)s * N_TOT + a];
    }
    float L = 0.f, V = 0.f;
    if (C > 0.f) {
        float lse = 10.0f + logf(E);
        L = -(10.0f * S - C * lse) / C;   // S stored in sim units
        V = 1.0f;
    }
#pragma unroll
    for (int m = 1; m < 64; m <<= 1) {
        L += __shfl_xor(L, m, 64);
        V += __shfl_xor(V, m, 64);
    }
    if (lane == 0) wsum[wave] = make_float2(L, V);
    __syncthreads();
    if (tid == 0) {
        float2 t = wsum[0];
        t.x += wsum[1].x + wsum[2].x + wsum[3].x;
        t.y += wsum[1].y + wsum[2].y + wsum[3].y;
        part[blockIdx.x] = t;
    }
}

// ---------------- finalize stage 2: reduce 32 partials ----------------
__global__ __launch_bounds__(64) void finalize2_kernel(const float2* __restrict__ part,
                                                       float* __restrict__ out) {
    int lane = threadIdx.x;
    float L = 0.f, V = 0.f;
    if (lane < 32) { float2 t = part[lane]; L = t.x; V = t.y; }
#pragma unroll
    for (int m = 1; m < 64; m <<= 1) {
        L += __shfl_xor(L, m, 64);
        V += __shfl_xor(V, m, 64);
    }
    if (lane == 0) out[0] = L / fmaxf(V, 1.0f);
}

extern "C" void kernel_launch(void* const* d_in, const int* in_sizes, int n_in,
                              void* d_out, int out_size, void* d_ws, size_t ws_size,
                              hipStream_t stream) {
    const float* h = (const float*)d_in[0];     // [8,1024,128] fp32
    const float* pos = (const float*)d_in[1];   // [8,1024,3] fp32
    float* out = (float*)d_out;                 // scalar fp32

    char* ws = (char*)d_ws;
    ushortT* hn = (ushortT*)ws;                                   // 2 MB bf16
    float4* p4 = (float4*)(ws + (size_t)N_TOT * D * 2);           // 128 KB
    char* p = ws + (size_t)N_TOT * D * 2 + (size_t)N_TOT * 16;
    float* Ep = (float*)p; p += (size_t)JSPLIT * N_TOT * 4;       // 256 KB
    float* Sp = (float*)p; p += (size_t)JSPLIT * N_TOT * 4;       // 256 KB
    float* Cp = (float*)p; p += (size_t)JSPLIT * N_TOT * 4;       // 256 KB
    float2* part = (float2*)p;                                    // 256 B

    prep_kernel<<<N_TOT / 16, 256, 0, stream>>>(h, pos, (unsigned*)hn, p4);
    main_kernel<<<dim3(N_TOT / 128, JSPLIT), 256, 0, stream>>>(hn, p4, Ep, Sp, Cp);
    finalize1_kernel<<<N_TOT / 256, 256, 0, stream>>>(Ep, Sp, Cp, part);
    finalize2_kernel<<<1, 64, 0, stream>>>(part, out);
}

// Round 4
// 167.855 us; speedup vs baseline: 1.1136x; 1.1136x over previous
//
#include <hip/hip_runtime.h>
#include <math.h>

#define N_TOT 8192
#define D 128
#define JSPLIT 8

typedef unsigned short ushortT;
typedef __attribute__((ext_vector_type(8))) short short8;
typedef __attribute__((ext_vector_type(4))) float f32x4;

// ---------------- bf16 pack (RNE) ----------------
__device__ __forceinline__ unsigned f2bf(float f) {
    unsigned u = __float_as_uint(f);
    return (u + 0x7FFF + ((u >> 16) & 1)) >> 16;
}
__device__ __forceinline__ unsigned pack2(float a, float b) {
    return f2bf(a) | (f2bf(b) << 16);
}

// ---------------- fused normalize->bf16 + pos pack ----------------
__global__ __launch_bounds__(256) void prep_kernel(const float* __restrict__ h,
                                                   const float* __restrict__ pos,
                                                   unsigned* __restrict__ hn2,
                                                   float4* __restrict__ p4) {
    const int tid = threadIdx.x;
    const int wave = tid >> 6, lane = tid & 63;
    const int quad = lane >> 4, l15 = lane & 15;
    const int row = blockIdx.x * 16 + wave * 4 + quad;

    const float4* g = reinterpret_cast<const float4*>(h + (size_t)row * D) + l15 * 2;
    float4 a = g[0], b = g[1];
    float ss = a.x * a.x + a.y * a.y + a.z * a.z + a.w * a.w
             + b.x * b.x + b.y * b.y + b.z * b.z + b.w * b.w;
#pragma unroll
    for (int m = 1; m < 16; m <<= 1) ss += __shfl_xor(ss, m, 64);
    float sc = 1.0f / fmaxf(sqrtf(ss), 1e-12f);

    uint4 o;
    o.x = pack2(a.x * sc, a.y * sc);
    o.y = pack2(a.z * sc, a.w * sc);
    o.z = pack2(b.x * sc, b.y * sc);
    o.w = pack2(b.z * sc, b.w * sc);
    reinterpret_cast<uint4*>(hn2 + (size_t)row * 64)[l15] = o;

    if (tid < 16) {
        int t = blockIdx.x * 16 + tid;
        float x = pos[3 * t], y = pos[3 * t + 1], z = pos[3 * t + 2];
        p4[t] = make_float4(x, y, z, x * x + y * y + z * z);
    }
}

// ---------------- stage a 128x128 bf16 tile via global_load_lds, XOR-swizzled ----------------
// LDS: row r holds logical 16B chunk k at physical chunk (k ^ (r&7)). global_load_lds's LDS
// side is fixed (base + lane*16), so the swizzle is realized by permuting the GLOBAL source
// per lane (permutation stays within the same 256B row -> same cache lines).
__device__ __forceinline__ void stage128(const ushortT* __restrict__ src, ushortT* dst,
                                         int wave, int lane) {
#pragma unroll
    for (int it = 0; it < 8; ++it) {
        int c = it * 4 + wave;                       // 1 KB chunk (4 rows)
        int rho = c * 4 + (lane >> 4);               // physical row this lane fills
        int k = (lane & 15) ^ (rho & 7);             // logical chunk to fetch
        const ushortT* g = src + (size_t)rho * D + k * 8;
        __builtin_amdgcn_global_load_lds(
            (const __attribute__((address_space(1))) unsigned int*)g,
            (__attribute__((address_space(3))) unsigned int*)(dst + c * 512),
            16, 0, 0);
    }
}

__device__ __forceinline__ int swz(int r, int k) {
    return r * D + ((k ^ (r & 7)) * 8);
}

// ---------------- fused MFMA sim + softmax partials + positive mask ----------------
// Key structure vs round 3: epilogue fused per j-column (acc live-set 8 regs, not 64),
// single predicated epilogue, B double-buffered with ONE barrier per tile.
__global__ __launch_bounds__(256, 2) void main_kernel(const ushortT* __restrict__ hn,
                                                      const float4* __restrict__ p4,
                                                      float* __restrict__ Ep,
                                                      float* __restrict__ Sp,
                                                      float* __restrict__ Cp) {
    __shared__ ushortT Bs[2][128 * D];               // 2 x 32 KB ping-pong
    const int tid = threadIdx.x;
    const int wave = tid >> 6, lane = tid & 63;
    const int quad = lane >> 4, l15 = lane & 15;
    const int iblock = blockIdx.x * 128;
    const int jstart = blockIdx.y * (N_TOT / JSPLIT);

    stage128(hn + (size_t)iblock * D, Bs[1], wave, lane);   // A-tile -> buf1 (temporarily)
    stage128(hn + (size_t)jstart * D, Bs[0], wave, lane);   // B-tile 0 -> buf0

    // per-lane anchors: 8 i-rows, i = iblock + wave*32 + r*16 + quad*4 + v
    float pix[8], piy[8], piz[8], qiw[8];
#pragma unroll
    for (int idx = 0; idx < 8; ++idx) {
        int i = iblock + wave * 32 + (idx >> 2) * 16 + quad * 4 + (idx & 3);
        float4 p = p4[i];
        pix[idx] = p.x; piy[idx] = p.y; piz[idx] = p.z; qiw[idx] = 0.5f * p.w;
    }
    float Ea[8], Sa[8];
    int Ci[8];
#pragma unroll
    for (int idx = 0; idx < 8; ++idx) { Ea[idx] = 0.f; Sa[idx] = 0.f; Ci[idx] = 0; }

    __syncthreads();   // A + B0 staged

    // hoist A fragments (constant across all j-tiles): 8 frags = 32 VGPRs
    short8 afr[4][2];
#pragma unroll
    for (int ks = 0; ks < 4; ++ks)
#pragma unroll
        for (int r = 0; r < 2; ++r) {
            int ra = wave * 32 + r * 16 + l15;
            afr[ks][r] = *reinterpret_cast<const short8*>(&Bs[1][swz(ra, ks * 4 + quad)]);
        }
    __syncthreads();   // all waves done with buf1 -> it may be overwritten

    for (int jt = 0; jt < 8; ++jt) {
        const int jtbase = jstart + jt * 128;
        // stage next tile into the other buffer; drains at this iteration's END barrier,
        // so it overlaps the full compute+epilogue below
        if (jt < 7)
            stage128(hn + (size_t)(jtbase + 128) * D, Bs[(jt + 1) & 1], wave, lane);

        const ushortT* B = Bs[jt & 1];
        const bool diag = (jtbase == iblock);

#pragma unroll
        for (int c = 0; c < 8; ++c) {
            short8 b[4];
#pragma unroll
            for (int ks = 0; ks < 4; ++ks)
                b[ks] = *reinterpret_cast<const short8*>(&B[swz(c * 16 + l15, ks * 4 + quad)]);

            f32x4 acc[2];
            acc[0] = (f32x4){0.f, 0.f, 0.f, 0.f};
            acc[1] = (f32x4){0.f, 0.f, 0.f, 0.f};
#pragma unroll
            for (int ks = 0; ks < 4; ++ks) {
                acc[0] = __builtin_amdgcn_mfma_f32_16x16x32_bf16(afr[ks][0], b[ks], acc[0], 0, 0, 0);
                acc[1] = __builtin_amdgcn_mfma_f32_16x16x32_bf16(afr[ks][1], b[ks], acc[1], 0, 0, 0);
            }

            // epilogue for this 16-column strip
            int j = jtbase + c * 16 + l15;
            float4 pj = p4[j];
            float thr = 0.5f * pj.w - 0.125f;
#pragma unroll
            for (int r = 0; r < 2; ++r)
#pragma unroll
                for (int v = 0; v < 4; ++v) {
                    int idx = r * 4 + v;
                    float s = acc[r][v];
                    bool self = diag && ((wave * 32 + r * 16 + quad * 4 + v) == (c * 16 + l15));
                    float e = __expf(fmaf(s, 10.f, -10.f));
                    Ea[idx] += self ? 0.f : e;
                    float dot = fmaf(pix[idx], pj.x, fmaf(piy[idx], pj.y, piz[idx] * pj.z));
                    bool isp = (dot > thr + qiw[idx]) && !self;
                    Sa[idx] += isp ? s : 0.f;
                    Ci[idx] += isp ? 1 : 0;
                }
        }
        __syncthreads();   // drains next-tile staging; all waves done reading B
    }

    // reduce across the 16 lanes (l15) sharing each i-row
#pragma unroll
    for (int idx = 0; idx < 8; ++idx) {
        float Cf = (float)Ci[idx];
#pragma unroll
        for (int m = 1; m < 16; m <<= 1) {
            Ea[idx] += __shfl_xor(Ea[idx], m, 64);
            Sa[idx] += __shfl_xor(Sa[idx], m, 64);
            Cf += __shfl_xor(Cf, m, 64);
        }
        if (l15 == 0) {
            int i = iblock + wave * 32 + (idx >> 2) * 16 + quad * 4 + (idx & 3);
            size_t o = (size_t)blockIdx.y * N_TOT + i;
            Ep[o] = Ea[idx]; Sp[o] = Sa[idx]; Cp[o] = Cf;
        }
    }
}

// ---------------- finalize stage 1: per-anchor loss, per-block partial ----------------
__global__ __launch_bounds__(256) void finalize1_kernel(const float* __restrict__ Ep,
                                                        const float* __restrict__ Sp,
                                                        const float* __restrict__ Cp,
                                                        float2* __restrict__ part) {
    __shared__ float2 wsum[4];
    const int tid = threadIdx.x;
    const int wave = tid >> 6, lane = tid & 63;
    const int a = blockIdx.x * 256 + tid;
    float E = 0.f, S = 0.f, C = 0.f;
#pragma unroll
    for (int s = 0; s < JSPLIT; ++s) {
        E += Ep[(size_t)s * N_TOT + a];
        S += Sp[(size_t)s * N_TOT + a];
        C += Cp[(size_t)s * N_TOT + a];
    }
    float L = 0.f, V = 0.f;
    if (C > 0.f) {
        float lse = 10.0f + logf(E);
        L = -(10.0f * S - C * lse) / C;   // S stored in sim units
        V = 1.0f;
    }
#pragma unroll
    for (int m = 1; m < 64; m <<= 1) {
        L += __shfl_xor(L, m, 64);
        V += __shfl_xor(V, m, 64);
    }
    if (lane == 0) wsum[wave] = make_float2(L, V);
    __syncthreads();
    if (tid == 0) {
        float2 t = wsum[0];
        t.x += wsum[1].x + wsum[2].x + wsum[3].x;
        t.y += wsum[1].y + wsum[2].y + wsum[3].y;
        part[blockIdx.x] = t;
    }
}

// ---------------- finalize stage 2: reduce 32 partials ----------------
__global__ __launch_bounds__(64) void finalize2_kernel(const float2* __restrict__ part,
                                                       float* __restrict__ out) {
    int lane = threadIdx.x;
    float L = 0.f, V = 0.f;
    if (lane < 32) { float2 t = part[lane]; L = t.x; V = t.y; }
#pragma unroll
    for (int m = 1; m < 64; m <<= 1) {
        L += __shfl_xor(L, m, 64);
        V += __shfl_xor(V, m, 64);
    }
    if (lane == 0) out[0] = L / fmaxf(V, 1.0f);
}

extern "C" void kernel_launch(void* const* d_in, const int* in_sizes, int n_in,
                              void* d_out, int out_size, void* d_ws, size_t ws_size,
                              hipStream_t stream) {
    const float* h = (const float*)d_in[0];     // [8,1024,128] fp32
    const float* pos = (const float*)d_in[1];   // [8,1024,3] fp32
    float* out = (float*)d_out;                 // scalar fp32

    char* ws = (char*)d_ws;
    ushortT* hn = (ushortT*)ws;                                   // 2 MB bf16
    float4* p4 = (float4*)(ws + (size_t)N_TOT * D * 2);           // 128 KB
    char* p = ws + (size_t)N_TOT * D * 2 + (size_t)N_TOT * 16;
    float* Ep = (float*)p; p += (size_t)JSPLIT * N_TOT * 4;       // 256 KB
    float* Sp = (float*)p; p += (size_t)JSPLIT * N_TOT * 4;       // 256 KB
    float* Cp = (float*)p; p += (size_t)JSPLIT * N_TOT * 4;       // 256 KB
    float2* part = (float2*)p;                                    // 256 B

    prep_kernel<<<N_TOT / 16, 256, 0, stream>>>(h, pos, (unsigned*)hn, p4);
    main_kernel<<<dim3(N_TOT / 128, JSPLIT), 256, 0, stream>>>(hn, p4, Ep, Sp, Cp);
    finalize1_kernel<<<N_TOT / 256, 256, 0, stream>>>(Ep, Sp, Cp, part);
    finalize2_kernel<<<1, 64, 0, stream>>>(part, out);
}

// Round 5
// 137.760 us; speedup vs baseline: 1.3569x; 1.2185x over previous
//
#include <hip/hip_runtime.h>
#include <math.h>

#define N_TOT 8192
#define D 128
#define JSPLIT 8

typedef unsigned short ushortT;
typedef __attribute__((ext_vector_type(8))) short short8;
typedef __attribute__((ext_vector_type(4))) float f32x4;

// ---------------- bf16 pack (RNE) ----------------
__device__ __forceinline__ unsigned f2bf(float f) {
    unsigned u = __float_as_uint(f);
    return (u + 0x7FFF + ((u >> 16) & 1)) >> 16;
}
__device__ __forceinline__ unsigned pack2(float a, float b) {
    return f2bf(a) | (f2bf(b) << 16);
}

// ---------------- fused normalize->bf16 + pos pack ----------------
__global__ __launch_bounds__(256) void prep_kernel(const float* __restrict__ h,
                                                   const float* __restrict__ pos,
                                                   unsigned* __restrict__ hn2,
                                                   float4* __restrict__ p4) {
    const int tid = threadIdx.x;
    const int wave = tid >> 6, lane = tid & 63;
    const int quad = lane >> 4, l15 = lane & 15;
    const int row = blockIdx.x * 16 + wave * 4 + quad;

    const float4* g = reinterpret_cast<const float4*>(h + (size_t)row * D) + l15 * 2;
    float4 a = g[0], b = g[1];
    float ss = a.x * a.x + a.y * a.y + a.z * a.z + a.w * a.w
             + b.x * b.x + b.y * b.y + b.z * b.z + b.w * b.w;
#pragma unroll
    for (int m = 1; m < 16; m <<= 1) ss += __shfl_xor(ss, m, 64);
    float sc = 1.0f / fmaxf(sqrtf(ss), 1e-12f);

    uint4 o;
    o.x = pack2(a.x * sc, a.y * sc);
    o.y = pack2(a.z * sc, a.w * sc);
    o.z = pack2(b.x * sc, b.y * sc);
    o.w = pack2(b.z * sc, b.w * sc);
    reinterpret_cast<uint4*>(hn2 + (size_t)row * 64)[l15] = o;

    if (tid < 16) {
        int t = blockIdx.x * 16 + tid;
        float x = pos[3 * t], y = pos[3 * t + 1], z = pos[3 * t + 2];
        p4[t] = make_float4(x, y, z, x * x + y * y + z * z);
    }
}

// ---------------- stage a 128x128 bf16 tile via global_load_lds, XOR-swizzled ----------------
// LDS: row r holds logical 16B chunk k at physical chunk (k ^ (r&7)). global_load_lds's LDS
// side is fixed (base + lane*16), so the swizzle is realized by permuting the GLOBAL source
// per lane (permutation stays within the same 256B row -> same cache lines).
__device__ __forceinline__ void stage128(const ushortT* __restrict__ src, ushortT* dst,
                                         int wave, int lane) {
#pragma unroll
    for (int it = 0; it < 8; ++it) {
        int c = it * 4 + wave;                       // 1 KB chunk (4 rows)
        int rho = c * 4 + (lane >> 4);               // physical row this lane fills
        int k = (lane & 15) ^ (rho & 7);             // logical chunk to fetch
        const ushortT* g = src + (size_t)rho * D + k * 8;
        __builtin_amdgcn_global_load_lds(
            (const __attribute__((address_space(1))) unsigned int*)g,
            (__attribute__((address_space(3))) unsigned int*)(dst + c * 512),
            16, 0, 0);
    }
}

__device__ __forceinline__ int swz(int r, int k) {
    return r * D + ((k ^ (r & 7)) * 8);
}

// ---------------- fused MFMA sim + softmax partials + positive mask ----------------
// __launch_bounds__(256, 1): LDS (64 KB) already caps occupancy at 2 blocks/CU; capping
// VGPRs at 128 (the (256,2) allocation) only forced ~250 B/thread of scratch spill
// (rocprof: WRITE_SIZE 32.5 MB vs 768 KB of real writes). Budget 512 -> no spill.
__global__ __launch_bounds__(256, 1) void main_kernel(const ushortT* __restrict__ hn,
                                                      const float4* __restrict__ p4,
                                                      float* __restrict__ Ep,
                                                      float* __restrict__ Sp,
                                                      float* __restrict__ Cp) {
    __shared__ ushortT Bs[2][128 * D];               // 2 x 32 KB ping-pong
    const int tid = threadIdx.x;
    const int wave = tid >> 6, lane = tid & 63;
    const int quad = lane >> 4, l15 = lane & 15;
    const int iblock = blockIdx.x * 128;
    const int jstart = blockIdx.y * (N_TOT / JSPLIT);

    stage128(hn + (size_t)iblock * D, Bs[1], wave, lane);   // A-tile -> buf1 (temporarily)
    stage128(hn + (size_t)jstart * D, Bs[0], wave, lane);   // B-tile 0 -> buf0

    // per-lane anchors: 8 i-rows, i = iblock + wave*32 + r*16 + quad*4 + v
    float pix[8], piy[8], piz[8], qiw[8];
#pragma unroll
    for (int idx = 0; idx < 8; ++idx) {
        int i = iblock + wave * 32 + (idx >> 2) * 16 + quad * 4 + (idx & 3);
        float4 p = p4[i];
        pix[idx] = p.x; piy[idx] = p.y; piz[idx] = p.z; qiw[idx] = 0.5f * p.w;
    }
    float Ea[8], Sa[8];
    int Ci[8];
#pragma unroll
    for (int idx = 0; idx < 8; ++idx) { Ea[idx] = 0.f; Sa[idx] = 0.f; Ci[idx] = 0; }

    __syncthreads();   // A + B0 staged

    // hoist A fragments (constant across all j-tiles): 8 frags = 32 VGPRs
    short8 afr[4][2];
#pragma unroll
    for (int ks = 0; ks < 4; ++ks)
#pragma unroll
        for (int r = 0; r < 2; ++r) {
            int ra = wave * 32 + r * 16 + l15;
            afr[ks][r] = *reinterpret_cast<const short8*>(&Bs[1][swz(ra, ks * 4 + quad)]);
        }
    __syncthreads();   // all waves done with buf1 -> it may be overwritten

    for (int jt = 0; jt < 8; ++jt) {
        const int jtbase = jstart + jt * 128;
        // stage next tile into the other buffer; drains at this iteration's END barrier,
        // so it overlaps the full compute+epilogue below
        if (jt < 7)
            stage128(hn + (size_t)(jtbase + 128) * D, Bs[(jt + 1) & 1], wave, lane);

        const ushortT* B = Bs[jt & 1];
        const bool diag = (jtbase == iblock);

#pragma unroll
        for (int c = 0; c < 8; ++c) {
            short8 b[4];
#pragma unroll
            for (int ks = 0; ks < 4; ++ks)
                b[ks] = *reinterpret_cast<const short8*>(&B[swz(c * 16 + l15, ks * 4 + quad)]);

            f32x4 acc[2];
            acc[0] = (f32x4){0.f, 0.f, 0.f, 0.f};
            acc[1] = (f32x4){0.f, 0.f, 0.f, 0.f};
#pragma unroll
            for (int ks = 0; ks < 4; ++ks) {
                acc[0] = __builtin_amdgcn_mfma_f32_16x16x32_bf16(afr[ks][0], b[ks], acc[0], 0, 0, 0);
                acc[1] = __builtin_amdgcn_mfma_f32_16x16x32_bf16(afr[ks][1], b[ks], acc[1], 0, 0, 0);
            }

            // epilogue for this 16-column strip
            int j = jtbase + c * 16 + l15;
            float4 pj = p4[j];
            float thr = 0.5f * pj.w - 0.125f;
#pragma unroll
            for (int r = 0; r < 2; ++r)
#pragma unroll
                for (int v = 0; v < 4; ++v) {
                    int idx = r * 4 + v;
                    float s = acc[r][v];
                    bool self = diag && ((wave * 32 + r * 16 + quad * 4 + v) == (c * 16 + l15));
                    float e = __expf(fmaf(s, 10.f, -10.f));
                    Ea[idx] += self ? 0.f : e;
                    float dot = fmaf(pix[idx], pj.x, fmaf(piy[idx], pj.y, piz[idx] * pj.z));
                    bool isp = (dot > thr + qiw[idx]) && !self;
                    Sa[idx] += isp ? s : 0.f;
                    Ci[idx] += isp ? 1 : 0;
                }
        }
        __syncthreads();   // drains next-tile staging; all waves done reading B
    }

    // reduce across the 16 lanes (l15) sharing each i-row
#pragma unroll
    for (int idx = 0; idx < 8; ++idx) {
        float Cf = (float)Ci[idx];
#pragma unroll
        for (int m = 1; m < 16; m <<= 1) {
            Ea[idx] += __shfl_xor(Ea[idx], m, 64);
            Sa[idx] += __shfl_xor(Sa[idx], m, 64);
            Cf += __shfl_xor(Cf, m, 64);
        }
        if (l15 == 0) {
            int i = iblock + wave * 32 + (idx >> 2) * 16 + quad * 4 + (idx & 3);
            size_t o = (size_t)blockIdx.y * N_TOT + i;
            Ep[o] = Ea[idx]; Sp[o] = Sa[idx]; Cp[o] = Cf;
        }
    }
}

// ---------------- finalize: per-anchor loss + mean over valid (single block) ----------------
__global__ __launch_bounds__(1024) void finalize_kernel(const float* __restrict__ Ep,
                                                        const float* __restrict__ Sp,
                                                        const float* __restrict__ Cp,
                                                        float* __restrict__ out) {
    __shared__ float2 wsum[16];
    const int tid = threadIdx.x;
    const int wave = tid >> 6, lane = tid & 63;
    float sumL = 0.f, sumV = 0.f;
#pragma unroll
    for (int blk = 0; blk < 8; ++blk) {
        int a = blk * 1024 + tid;
        float E = 0.f, S = 0.f, C = 0.f;
#pragma unroll
        for (int s = 0; s < JSPLIT; ++s) {
            E += Ep[(size_t)s * N_TOT + a];
            S += Sp[(size_t)s * N_TOT + a];
            C += Cp[(size_t)s * N_TOT + a];
        }
        if (C > 0.f) {
            float lse = 10.0f + logf(E);
            sumL += -(10.0f * S - C * lse) / C;   // S stored in sim units
            sumV += 1.0f;
        }
    }
#pragma unroll
    for (int m = 1; m < 64; m <<= 1) {
        sumL += __shfl_xor(sumL, m, 64);
        sumV += __shfl_xor(sumV, m, 64);
    }
    if (lane == 0) wsum[wave] = make_float2(sumL, sumV);
    __syncthreads();
    if (tid == 0) {
        float L = 0.f, V = 0.f;
#pragma unroll
        for (int w = 0; w < 16; ++w) { L += wsum[w].x; V += wsum[w].y; }
        out[0] = L / fmaxf(V, 1.0f);
    }
}

extern "C" void kernel_launch(void* const* d_in, const int* in_sizes, int n_in,
                              void* d_out, int out_size, void* d_ws, size_t ws_size,
                              hipStream_t stream) {
    const float* h = (const float*)d_in[0];     // [8,1024,128] fp32
    const float* pos = (const float*)d_in[1];   // [8,1024,3] fp32
    float* out = (float*)d_out;                 // scalar fp32

    char* ws = (char*)d_ws;
    ushortT* hn = (ushortT*)ws;                                   // 2 MB bf16
    float4* p4 = (float4*)(ws + (size_t)N_TOT * D * 2);           // 128 KB
    char* p = ws + (size_t)N_TOT * D * 2 + (size_t)N_TOT * 16;
    float* Ep = (float*)p; p += (size_t)JSPLIT * N_TOT * 4;       // 256 KB
    float* Sp = (float*)p; p += (size_t)JSPLIT * N_TOT * 4;       // 256 KB
    float* Cp = (float*)p;                                        // 256 KB

    prep_kernel<<<N_TOT / 16, 256, 0, stream>>>(h, pos, (unsigned*)hn, p4);
    main_kernel<<<dim3(N_TOT / 128, JSPLIT), 256, 0, stream>>>(hn, p4, Ep, Sp, Cp);
    finalize_kernel<<<1, 1024, 0, stream>>>(Ep, Sp, Cp, out);
}